// Round 4
// baseline (340.070 us; speedup 1.0000x reference)
//
#include <hip/hip_runtime.h>
#include <hip/hip_bf16.h>

typedef __attribute__((ext_vector_type(8))) short short8;
typedef __attribute__((ext_vector_type(4))) float f32x4;
typedef __attribute__((ext_vector_type(2))) unsigned int u32x2;
typedef __attribute__((ext_vector_type(4))) unsigned int u32x4;

#define B_    2
#define L_    2048
#define DIM_  1024
#define NH_   16
#define HEAD_ 64
#define M_    4096            // B_*L_
#define SZ_   4194304         // M_*DIM_ elements
#define SCL   0.18033688011112043f   // 0.125 * log2(e)

__device__ __forceinline__ unsigned short f2bf(float f) {
  __hip_bfloat16 h = __float2bfloat16(f);   // RNE; compiles to v_cvt_pk_bf16_f32
  return __builtin_bit_cast(unsigned short, h);
}
__device__ __forceinline__ unsigned int pk2(float a, float b) {
  return (unsigned int)f2bf(a) | ((unsigned int)f2bf(b) << 16);
}

// C[m][n] = sum_k A[m][k] * W[n][k]; tile 128x64, BK=64, 256 thr, reg-prefetch.
// OUT: 0 = bf16 row-major, 1 = f32 row-major, 2 = bf16 VT'[bh][d][c][lrow]
template<bool A_F32, int OUT>
__global__ __launch_bounds__(256) void gemm_bt(const void* __restrict__ Ap,
                                               const float* __restrict__ Wp,
                                               void* __restrict__ Cp,
                                               int Kdim, int Ndim) {
  __shared__ unsigned short Alds[128][72];
  __shared__ unsigned short Blds[64][72];
  const int t = threadIdx.x;
  // XCD-chunked swizzle: XCD k gets m-tiles 4k..4k+3 (A panels L2-resident)
  const int lin = blockIdx.x;
  const int swz = (lin & 7) * 64 + (lin >> 3);
  const int m0 = (swz >> 4) * 128;
  const int n0 = (swz & 15) * 64;
  const int lane = t & 63;
  const int wid  = t >> 6;
  const int lr   = lane & 15;
  const int lg   = lane >> 4;
  const int wm   = (wid >> 1) * 64;
  const int wn   = (wid & 1) * 32;
  const int arow = t & 127, ac0 = (t >> 7) * 32;   // A: 32 elems/thread
  const int brow = t & 63,  bc0 = (t >> 6) * 16;   // B: 16 elems/thread

  f32x4 aR[8]; short8 aR16[4]; f32x4 bR[4];
  f32x4 acc[4][2] = {};

  auto loadT = [&](int kb) {
    if (A_F32) {
      const float* p = (const float*)Ap + (size_t)(m0 + arow) * Kdim + kb + ac0;
#pragma unroll
      for (int j = 0; j < 8; ++j) aR[j] = ((const f32x4*)p)[j];
    } else {
      const unsigned short* p = (const unsigned short*)Ap + (size_t)(m0 + arow) * Kdim + kb + ac0;
#pragma unroll
      for (int j = 0; j < 4; ++j) aR16[j] = ((const short8*)p)[j];
    }
    const float* q = Wp + (size_t)(n0 + brow) * Kdim + kb + bc0;
#pragma unroll
    for (int j = 0; j < 4; ++j) bR[j] = ((const f32x4*)q)[j];
  };
  auto storeT = [&]() {
    if (A_F32) {
      u32x4 w[4];
#pragma unroll
      for (int j = 0; j < 8; ++j) {
        w[j >> 1][(j & 1) * 2]     = pk2(aR[j][0], aR[j][1]);
        w[j >> 1][(j & 1) * 2 + 1] = pk2(aR[j][2], aR[j][3]);
      }
#pragma unroll
      for (int j = 0; j < 4; ++j) *(u32x4*)&Alds[arow][ac0 + j * 8] = w[j];
    } else {
#pragma unroll
      for (int j = 0; j < 4; ++j) *(short8*)&Alds[arow][ac0 + j * 8] = aR16[j];
    }
    u32x4 w[2];
#pragma unroll
    for (int j = 0; j < 4; ++j) {
      w[j >> 1][(j & 1) * 2]     = pk2(bR[j][0], bR[j][1]);
      w[j >> 1][(j & 1) * 2 + 1] = pk2(bR[j][2], bR[j][3]);
    }
#pragma unroll
    for (int j = 0; j < 2; ++j) *(u32x4*)&Blds[brow][bc0 + j * 8] = w[j];
  };

  loadT(0);
  for (int kb = 0; kb < Kdim; kb += 64) {
    __syncthreads();
    storeT();
    if (kb + 64 < Kdim) loadT(kb + 64);
    __syncthreads();
#pragma unroll
    for (int ks = 0; ks < 2; ++ks) {
      short8 af[4], bfv[2];
#pragma unroll
      for (int i = 0; i < 4; ++i)
        af[i] = *(const short8*)&Alds[wm + i * 16 + lr][ks * 32 + lg * 8];
#pragma unroll
      for (int j = 0; j < 2; ++j)
        bfv[j] = *(const short8*)&Blds[wn + j * 16 + lr][ks * 32 + lg * 8];
#pragma unroll
      for (int i = 0; i < 4; ++i)
#pragma unroll
        for (int j = 0; j < 2; ++j)
          acc[i][j] = __builtin_amdgcn_mfma_f32_16x16x32_bf16(af[i], bfv[j], acc[i][j], 0, 0, 0);
    }
  }

#pragma unroll
  for (int i = 0; i < 4; ++i) {
#pragma unroll
    for (int j = 0; j < 2; ++j) {
      const int grow = m0 + wm + i * 16 + lg * 4;
      const int gcol = n0 + wn + j * 16 + lr;
      if (OUT == 2) {
        const int bh_  = grow >> 7;
        const int lrow = grow & 127;
        const int dd   = gcol & 63;
        const int cc   = gcol >> 6;
        u32x2 pk;
        pk[0] = pk2(acc[i][j][0], acc[i][j][1]);
        pk[1] = pk2(acc[i][j][2], acc[i][j][3]);
        size_t off = ((size_t)(bh_ * 64 + dd) * 16 + cc) * 128 + lrow;
        *(u32x2*)&((unsigned short*)Cp)[off] = pk;
      } else {
#pragma unroll
        for (int r = 0; r < 4; ++r) {
          float v = acc[i][j][r];
          if (OUT == 1) ((float*)Cp)[(size_t)(grow + r) * Ndim + gcol] = v;
          else ((unsigned short*)Cp)[(size_t)(grow + r) * Ndim + gcol] = f2bf(v);
        }
      }
    }
  }
}

// Flash attention: 4 waves, QBLK=64 (16 q-rows/wave), 64-key chunks.
// Grid 1024 -> 4 blocks/CU. Defer-max rescale (THR=16 raw-score units).
__global__ __launch_bounds__(256) void attn_flash(const unsigned short* __restrict__ QKV,
                                                  const unsigned short* __restrict__ VTg,
                                                  unsigned short* __restrict__ Xout) {
  __shared__ unsigned short Klds[64 * 64];     // 8 KB, swizzled rows of 128B
  __shared__ unsigned short VTlds[64 * 64];    // 8 KB, permuted key order
  __shared__ unsigned short Plds[4][16 * 64];  // 2 KB per wave

  const int t    = threadIdx.x;
  const int wv   = t >> 6;
  const int lane = t & 63;
  const int lr   = lane & 15;
  const int lg   = lane >> 4;
  // XCD k handles heads 4k..4k+3 -> K/VT stay L2-resident (~2 MB per XCD)
  const int lin = blockIdx.x;
  const int xcd = lin & 7;
  const int r_  = lin >> 3;          // 0..127
  const int bh  = xcd * 4 + (r_ >> 5);
  const int qt  = r_ & 31;           // 0..31
  const int b   = bh >> 4;
  const int h   = bh & 15;
  const size_t base = (size_t)b * (L_ * DIM_) + (size_t)h * (L_ * HEAD_);
  const unsigned short* Qp  = QKV + base;
  const unsigned short* Kp  = QKV + (size_t)SZ_ + base;
  const unsigned short* VTp = VTg + (size_t)bh * (HEAD_ * L_);
  const int q0 = qt * 64;

  short8 qf[2];
#pragma unroll
  for (int ks = 0; ks < 2; ++ks)
    qf[ks] = *(const short8*)&Qp[(size_t)(q0 + wv * 16 + lr) * 64 + ks * 32 + lg * 8];

  f32x4 oacc[4] = {};
  f32x4 lsum = {};
  f32x4 mrun;
#pragma unroll
  for (int c = 0; c < 4; ++c) mrun[c] = -3.0e38f;

  for (int jb = 0; jb < L_; jb += 64) {
    if (jb) __syncthreads();
    // ---- stage K chunk (64 keys x 64d), swizzled
#pragma unroll
    for (int s = 0; s < 2; ++s) {
      const int idx = s * 256 + t;
      const int row = idx >> 3;
      const int c8  = idx & 7;
      const int dst = row * 128 + ((c8 * 16) ^ ((row & 7) << 4));
      *(short8*)((char*)Klds + dst) = *(const short8*)&Kp[(size_t)(jb + row) * 64 + c8 * 8];
    }
    // ---- stage VT' chunk: row d, position p=c*4+l holds key jb + 16*l + c
#pragma unroll
    for (int s = 0; s < 4; ++s) {
      const int idx = s * 256 + t;
      const int d   = idx >> 4;
      const int c   = idx & 15;
      u32x2 w = *(const u32x2*)&VTp[(size_t)d * (16 * 128) + c * 128 + (jb >> 4)];
      *(u32x2*)((char*)VTlds + d * 128 + ((c * 8) ^ ((d & 7) << 4))) = w;
    }
    __syncthreads();

    // ---- QK^T : sacc[jf], q-row = wv*16 + lg*4+c, key = jb + jf*16+lr
    f32x4 sacc[4] = {};
#pragma unroll
    for (int jf = 0; jf < 4; ++jf) {
      const int row = jf * 16 + lr;
#pragma unroll
      for (int ks = 0; ks < 2; ++ks) {
        short8 kf = *(const short8*)((const char*)Klds + row * 128 + ((ks * 64 + lg * 16) ^ ((row & 7) << 4)));
        sacc[jf] = __builtin_amdgcn_mfma_f32_16x16x32_bf16(qf[ks], kf, sacc[jf], 0, 0, 0);
      }
    }

    // ---- online softmax with defer-max
    f32x4 mc = sacc[0];
#pragma unroll
    for (int jf = 1; jf < 4; ++jf)
#pragma unroll
      for (int c = 0; c < 4; ++c) mc[c] = fmaxf(mc[c], sacc[jf][c]);
#pragma unroll
    for (int c = 0; c < 4; ++c) {
      float m = mc[c];
      m = fmaxf(m, __shfl_xor(m, 1, 64));
      m = fmaxf(m, __shfl_xor(m, 2, 64));
      m = fmaxf(m, __shfl_xor(m, 4, 64));
      m = fmaxf(m, __shfl_xor(m, 8, 64));
      mc[c] = m;
    }
    int ok = (mc[0] <= mrun[0] + 16.f) & (mc[1] <= mrun[1] + 16.f) &
             (mc[2] <= mrun[2] + 16.f) & (mc[3] <= mrun[3] + 16.f);
    if (!__all(ok)) {
      f32x4 sc;
#pragma unroll
      for (int c = 0; c < 4; ++c) {
        float mnew = fmaxf(mrun[c], mc[c]);
        sc[c] = exp2f((mrun[c] - mnew) * SCL);
        mrun[c] = mnew;
        lsum[c] *= sc[c];
      }
#pragma unroll
      for (int nf = 0; nf < 4; ++nf)
#pragma unroll
        for (int c = 0; c < 4; ++c) oacc[nf][c] *= sc[c];
    }
    // P store (permuted): key jf*16+lr -> byte lr*8 + jf*2 -> one 8B store/c
#pragma unroll
    for (int c = 0; c < 4; ++c) {
      float p0 = exp2f((sacc[0][c] - mrun[c]) * SCL);
      float p1 = exp2f((sacc[1][c] - mrun[c]) * SCL);
      float p2 = exp2f((sacc[2][c] - mrun[c]) * SCL);
      float p3 = exp2f((sacc[3][c] - mrun[c]) * SCL);
      const int prow = lg * 4 + c;
      u32x2 pk;
      pk[0] = pk2(p0, p1);
      pk[1] = pk2(p2, p3);
      *(u32x2*)((char*)Plds[wv] + prow * 128 + ((lr * 8) ^ ((prow & 7) << 4))) = pk;
      lsum[c] += (p0 + p1) + (p2 + p3);
    }

    // ---- PV : oacc[nf] += P * V  (both operands in permuted key order)
#pragma unroll
    for (int kk = 0; kk < 2; ++kk) {
      short8 pa = *(const short8*)((const char*)Plds[wv] + lr * 128 + ((kk * 64 + lg * 16) ^ ((lr & 7) << 4)));
#pragma unroll
      for (int nf = 0; nf < 4; ++nf) {
        const int rv = nf * 16 + lr;
        short8 vf = *(const short8*)((const char*)VTlds + rv * 128 + ((kk * 64 + lg * 16) ^ ((rv & 7) << 4)));
        oacc[nf] = __builtin_amdgcn_mfma_f32_16x16x32_bf16(pa, vf, oacc[nf], 0, 0, 0);
      }
    }
  }

  // ---- finalize
#pragma unroll
  for (int c = 0; c < 4; ++c) {
    float s = lsum[c];
    s += __shfl_xor(s, 1, 64);
    s += __shfl_xor(s, 2, 64);
    s += __shfl_xor(s, 4, 64);
    s += __shfl_xor(s, 8, 64);
    lsum[c] = s;
  }
#pragma unroll
  for (int nf = 0; nf < 4; ++nf)
#pragma unroll
    for (int c = 0; c < 4; ++c) {
      const int row = q0 + wv * 16 + lg * 4 + c;
      Xout[(size_t)b * (L_ * DIM_) + (size_t)row * DIM_ + h * HEAD_ + nf * 16 + lr] =
          f2bf(oacc[nf][c] / lsum[c]);
    }
}

extern "C" void kernel_launch(void* const* d_in, const int* in_sizes, int n_in,
                              void* d_out, int out_size, void* d_ws, size_t ws_size,
                              hipStream_t stream) {
  (void)in_sizes; (void)n_in; (void)out_size; (void)ws_size;
  const float* q  = (const float*)d_in[0];
  const float* k  = (const float*)d_in[1];
  const float* v  = (const float*)d_in[2];
  const float* Wq = (const float*)d_in[3];
  const float* Wk = (const float*)d_in[4];
  const float* Wv = (const float*)d_in[5];
  const float* Wo = (const float*)d_in[6];

  unsigned short* wsu  = (unsigned short*)d_ws;
  unsigned short* qkv  = wsu;                    // Q, K bf16 (2*SZ_)
  unsigned short* vt   = wsu + 2 * (size_t)SZ_;  // VT' (SZ_)
  unsigned short* xout = wsu + 3 * (size_t)SZ_;

  gemm_bt<true, 0><<<512, 256, 0, stream>>>((const void*)q, Wq, (void*)(qkv + 0 * (size_t)SZ_), DIM_, DIM_);
  gemm_bt<true, 0><<<512, 256, 0, stream>>>((const void*)k, Wk, (void*)(qkv + 1 * (size_t)SZ_), DIM_, DIM_);
  gemm_bt<true, 2><<<512, 256, 0, stream>>>((const void*)v, Wv, (void*)vt, DIM_, DIM_);

  attn_flash<<<1024, 256, 0, stream>>>(qkv, vt, xout);

  gemm_bt<false, 1><<<512, 256, 0, stream>>>((const void*)xout, Wo, d_out, DIM_, DIM_);
}

// Round 5
// 251.040 us; speedup vs baseline: 1.3546x; 1.3546x over previous
//
#include <hip/hip_runtime.h>
#include <hip/hip_bf16.h>

typedef __attribute__((ext_vector_type(8))) short short8;
typedef __attribute__((ext_vector_type(4))) float f32x4;
typedef __attribute__((ext_vector_type(2))) unsigned int u32x2;
typedef __attribute__((ext_vector_type(4))) unsigned int u32x4;

#define B_    2
#define L_    2048
#define DIM_  1024
#define NH_   16
#define HEAD_ 64
#define M_    4096            // B_*L_
#define SZ_   4194304         // M_*DIM_ elements
#define WSZ_  1048576         // DIM_*DIM_
#define SCL   0.18033688011112043f   // 0.125 * log2(e)

__device__ __forceinline__ unsigned short f2bf(float f) {
  __hip_bfloat16 h = __float2bfloat16(f);
  return __builtin_bit_cast(unsigned short, h);
}
__device__ __forceinline__ unsigned int pk2(float a, float b) {
  return (unsigned int)f2bf(a) | ((unsigned int)f2bf(b) << 16);
}
__device__ __forceinline__ void gl_lds16(const void* g, void* l) {
  __builtin_amdgcn_global_load_lds(
      (const __attribute__((address_space(1))) unsigned int*)g,
      (__attribute__((address_space(3))) unsigned int*)l, 16, 0, 0);
}

// ---- fp32 -> bf16 weight conversion: 4 x 1M elems
__global__ __launch_bounds__(256) void cvt_w(const float* __restrict__ w0,
                                             const float* __restrict__ w1,
                                             const float* __restrict__ w2,
                                             const float* __restrict__ w3,
                                             unsigned short* __restrict__ out) {
  const int bid = blockIdx.x;                 // 0..2047
  const int w   = bid >> 9;
  const float* src = (w == 0) ? w0 : (w == 1) ? w1 : (w == 2) ? w2 : w3;
  const int idx = (bid & 511) * 2048 + threadIdx.x * 8;
  f32x4 a = *(const f32x4*)(src + idx);
  f32x4 b = *(const f32x4*)(src + idx + 4);
  u32x4 o;
  o[0] = pk2(a[0], a[1]); o[1] = pk2(a[2], a[3]);
  o[2] = pk2(b[0], b[1]); o[3] = pk2(b[2], b[3]);
  *(u32x4*)(out + (size_t)w * WSZ_ + idx) = o;
}

// C[m][n] = sum_k A[m][k] * W[n][k]; tile 128x64, BK=64, 256 thr.
// A_MODE 0: A fp32, reg-staged + cvt_pk, swizzled LDS write.
// A_MODE 1: A bf16, global_load_lds (linear dest, pre-swizzled source).
// B: always bf16 via global_load_lds. Reads are XOR-swizzled (conflict-free).
// OUT: 0 = bf16 row-major, 1 = f32 row-major, 2 = bf16 VT'[bh][d][c][lrow]
template<int A_MODE, int OUT>
__global__ __launch_bounds__(256) void gemm_bt(const void* __restrict__ Ap,
                                               const unsigned short* __restrict__ Wb,
                                               void* __restrict__ Cp) {
  constexpr int Kdim = 1024, Ndim = 1024;
  __shared__ unsigned short Alds[128 * 64];   // 16 KB
  __shared__ unsigned short Blds[64 * 64];    // 8 KB
  const int t   = threadIdx.x;
  // XCD-chunked swizzle: XCD k gets m-tiles 4k..4k+3 -> A panel + W L2-resident
  const int lin = blockIdx.x;
  const int swz = (lin & 7) * 64 + (lin >> 3);
  const int m0  = (swz >> 4) * 128;
  const int n0  = (swz & 15) * 64;
  const int lane = t & 63;
  const int wid  = t >> 6;
  const int lr = lane & 15, lg = lane >> 4;
  const int wm = (wid >> 1) * 64, wn = (wid & 1) * 32;
  const int arow = t & 127, agb = (t >> 7) * 4;   // A: 2 thr/row, 4 granules each

  f32x4 aR[8];
  f32x4 acc[4][2] = {};

  auto loadA = [&](int kb) {
    const float* p = (const float*)Ap + (size_t)(m0 + arow) * Kdim + kb + agb * 8;
#pragma unroll
    for (int j = 0; j < 8; ++j) aR[j] = ((const f32x4*)p)[j];
  };
  auto storeA = [&]() {
#pragma unroll
    for (int j = 0; j < 4; ++j) {
      u32x4 w;
      w[0] = pk2(aR[2 * j][0], aR[2 * j][1]);
      w[1] = pk2(aR[2 * j][2], aR[2 * j][3]);
      w[2] = pk2(aR[2 * j + 1][0], aR[2 * j + 1][1]);
      w[3] = pk2(aR[2 * j + 1][2], aR[2 * j + 1][3]);
      const int c = agb + j;
      *(u32x4*)((char*)Alds + arow * 128 + ((c * 16) ^ ((arow & 7) << 4))) = w;
    }
  };
  auto issueA = [&](int kb) {   // A_MODE 1: 4 x 4KB, linear dest, swizzled src
#pragma unroll
    for (int s = 0; s < 4; ++s) {
      const int row = s * 32 + wid * 8 + (lane >> 3);
      const int c   = (lane & 7) ^ (row & 7);
      gl_lds16((const unsigned short*)Ap + (size_t)(m0 + row) * Kdim + kb + c * 8,
               (char*)Alds + s * 4096 + wid * 1024);
    }
  };
  auto issueB = [&](int kb) {   // 2 x 4KB
#pragma unroll
    for (int s = 0; s < 2; ++s) {
      const int row = s * 32 + wid * 8 + (lane >> 3);
      const int c   = (lane & 7) ^ (row & 7);
      gl_lds16(Wb + (size_t)(n0 + row) * Kdim + kb + c * 8,
               (char*)Blds + s * 4096 + wid * 1024);
    }
  };

  if constexpr (A_MODE == 0) loadA(0);
  for (int kb = 0; kb < Kdim; kb += 64) {
    __syncthreads();                       // prev compute done; LDS free
    if constexpr (A_MODE == 0) storeA();
    else issueA(kb);
    issueB(kb);
    __syncthreads();                       // drains vmcnt+lgkm: tiles ready
    if constexpr (A_MODE == 0) { if (kb + 64 < Kdim) loadA(kb + 64); }
#pragma unroll
    for (int ks = 0; ks < 2; ++ks) {
      short8 af[4], bfv[2];
#pragma unroll
      for (int i = 0; i < 4; ++i) {
        const int r = wm + i * 16 + lr;
        af[i] = *(const short8*)((const char*)Alds + r * 128 + ((ks * 64 + lg * 16) ^ ((r & 7) << 4)));
      }
#pragma unroll
      for (int j = 0; j < 2; ++j) {
        const int r = wn + j * 16 + lr;
        bfv[j] = *(const short8*)((const char*)Blds + r * 128 + ((ks * 64 + lg * 16) ^ ((r & 7) << 4)));
      }
#pragma unroll
      for (int i = 0; i < 4; ++i)
#pragma unroll
        for (int j = 0; j < 2; ++j)
          acc[i][j] = __builtin_amdgcn_mfma_f32_16x16x32_bf16(af[i], bfv[j], acc[i][j], 0, 0, 0);
    }
  }

#pragma unroll
  for (int i = 0; i < 4; ++i) {
#pragma unroll
    for (int j = 0; j < 2; ++j) {
      const int grow = m0 + wm + i * 16 + lg * 4;
      const int gcol = n0 + wn + j * 16 + lr;
      if (OUT == 2) {
        const int bh_  = grow >> 7;
        const int lrow = grow & 127;
        const int dd   = gcol & 63;
        const int cc   = gcol >> 6;
        u32x2 pk;
        pk[0] = pk2(acc[i][j][0], acc[i][j][1]);
        pk[1] = pk2(acc[i][j][2], acc[i][j][3]);
        size_t off = ((size_t)(bh_ * 64 + dd) * 16 + cc) * 128 + lrow;
        *(u32x2*)&((unsigned short*)Cp)[off] = pk;
      } else {
#pragma unroll
        for (int r = 0; r < 4; ++r) {
          float v = acc[i][j][r];
          if (OUT == 1) ((float*)Cp)[(size_t)(grow + r) * Ndim + gcol] = v;
          else ((unsigned short*)Cp)[(size_t)(grow + r) * Ndim + gcol] = f2bf(v);
        }
      }
    }
  }
}

// Flash attention: 4 waves x 32 q-rows (QBLK=128), 64-key chunks, grid 512.
// Defer-max with pre-reduce check (shuffle reduce only on trigger chunks).
__global__ __launch_bounds__(256) void attn_flash(const unsigned short* __restrict__ QKV,
                                                  const unsigned short* __restrict__ VTg,
                                                  unsigned short* __restrict__ Xout) {
  __shared__ unsigned short Klds[64 * 64];     // 8 KB, swizzled rows of 128B
  __shared__ unsigned short VTlds[64 * 64];    // 8 KB, permuted key order
  __shared__ unsigned short Plds[4][32 * 64];  // 4 KB per wave, permuted order

  const int t    = threadIdx.x;
  const int wv   = t >> 6;
  const int lane = t & 63;
  const int lr   = lane & 15;
  const int lg   = lane >> 4;
  // XCD k handles heads 4k..4k+3 -> K/VT stay L2-resident (~2 MB per XCD)
  const int id  = blockIdx.x;
  const int xcd = id & 7;
  const int seq = id >> 3;          // 0..63
  const int bh  = xcd * 4 + (seq >> 4);
  const int qt  = seq & 15;
  const int b   = bh >> 4;
  const int h   = bh & 15;
  const size_t base = (size_t)b * (L_ * DIM_) + (size_t)h * (L_ * HEAD_);
  const unsigned short* Qp  = QKV + base;
  const unsigned short* Kp  = QKV + (size_t)SZ_ + base;
  const unsigned short* VTp = VTg + (size_t)bh * (HEAD_ * L_);
  const int q0 = qt * 128;

  short8 qf[2][2];
#pragma unroll
  for (int mf = 0; mf < 2; ++mf)
#pragma unroll
    for (int ks = 0; ks < 2; ++ks)
      qf[mf][ks] = *(const short8*)&Qp[(size_t)(q0 + wv * 32 + mf * 16 + lr) * 64 + ks * 32 + lg * 8];

  f32x4 oacc[2][4] = {};
  f32x4 lsum[2] = {};
  f32x4 mrun[2];
#pragma unroll
  for (int mf = 0; mf < 2; ++mf)
#pragma unroll
    for (int c = 0; c < 4; ++c) mrun[mf][c] = -3.0e38f;

  for (int jb = 0; jb < L_; jb += 64) {
    if (jb) __syncthreads();
    // ---- stage K chunk (64 keys x 64d), swizzled
#pragma unroll
    for (int s = 0; s < 2; ++s) {
      const int idx = s * 256 + t;
      const int row = idx >> 3;
      const int c8  = idx & 7;
      const int dst = row * 128 + ((c8 * 16) ^ ((row & 7) << 4));
      *(short8*)((char*)Klds + dst) = *(const short8*)&Kp[(size_t)(jb + row) * 64 + c8 * 8];
    }
    // ---- stage VT' chunk: row d, position p=c*4+l holds key jb + 16*l + c
#pragma unroll
    for (int s = 0; s < 4; ++s) {
      const int idx = s * 256 + t;
      const int d   = idx >> 4;
      const int c   = idx & 15;
      u32x2 w = *(const u32x2*)&VTp[(size_t)d * (16 * 128) + c * 128 + (jb >> 4)];
      *(u32x2*)((char*)VTlds + d * 128 + ((c * 8) ^ ((d & 7) << 4))) = w;
    }
    __syncthreads();

    // ---- QK^T : sacc[mf][jf], q-row = mf*16+lg*4+c, key = jb + jf*16+lr
    f32x4 sacc[2][4] = {};
#pragma unroll
    for (int jf = 0; jf < 4; ++jf) {
      const int row = jf * 16 + lr;
#pragma unroll
      for (int ks = 0; ks < 2; ++ks) {
        short8 kf = *(const short8*)((const char*)Klds + row * 128 + ((ks * 64 + lg * 16) ^ ((row & 7) << 4)));
#pragma unroll
        for (int mf = 0; mf < 2; ++mf)
          sacc[mf][jf] = __builtin_amdgcn_mfma_f32_16x16x32_bf16(qf[mf][ks], kf, sacc[mf][jf], 0, 0, 0);
      }
    }

    // ---- online softmax: defer-max, reduce only when triggered
    f32x4 mc[2];
    int okf = 1;
#pragma unroll
    for (int mf = 0; mf < 2; ++mf) {
      mc[mf] = sacc[mf][0];
#pragma unroll
      for (int jf = 1; jf < 4; ++jf)
#pragma unroll
        for (int c = 0; c < 4; ++c) mc[mf][c] = fmaxf(mc[mf][c], sacc[mf][jf][c]);
#pragma unroll
      for (int c = 0; c < 4; ++c)
        okf &= (mc[mf][c] <= mrun[mf][c] + 16.f) ? 1 : 0;
    }
    if (!__all(okf)) {
#pragma unroll
      for (int mf = 0; mf < 2; ++mf) {
        f32x4 sc;
#pragma unroll
        for (int c = 0; c < 4; ++c) {
          float m = mc[mf][c];
          m = fmaxf(m, __shfl_xor(m, 1, 64));
          m = fmaxf(m, __shfl_xor(m, 2, 64));
          m = fmaxf(m, __shfl_xor(m, 4, 64));
          m = fmaxf(m, __shfl_xor(m, 8, 64));
          float mnew = fmaxf(mrun[mf][c], m);
          sc[c] = exp2f((mrun[mf][c] - mnew) * SCL);
          mrun[mf][c] = mnew;
          lsum[mf][c] *= sc[c];
        }
#pragma unroll
        for (int nf = 0; nf < 4; ++nf)
#pragma unroll
          for (int c = 0; c < 4; ++c) oacc[mf][nf][c] *= sc[c];
      }
    }
    // ---- P pack (permuted): key jf*16+lr -> byte lr*8 + jf*2
#pragma unroll
    for (int mf = 0; mf < 2; ++mf)
#pragma unroll
      for (int c = 0; c < 4; ++c) {
        float p0 = exp2f((sacc[mf][0][c] - mrun[mf][c]) * SCL);
        float p1 = exp2f((sacc[mf][1][c] - mrun[mf][c]) * SCL);
        float p2 = exp2f((sacc[mf][2][c] - mrun[mf][c]) * SCL);
        float p3 = exp2f((sacc[mf][3][c] - mrun[mf][c]) * SCL);
        const int prow = mf * 16 + lg * 4 + c;
        u32x2 pk;
        pk[0] = pk2(p0, p1);
        pk[1] = pk2(p2, p3);
        *(u32x2*)((char*)Plds[wv] + prow * 128 + ((lr * 8) ^ ((prow & 7) << 4))) = pk;
        lsum[mf][c] += (p0 + p1) + (p2 + p3);
      }

    // ---- PV : oacc[mf][nf] += P * V  (both operands in permuted key order)
#pragma unroll
    for (int kk = 0; kk < 2; ++kk) {
      short8 pa[2];
#pragma unroll
      for (int mf = 0; mf < 2; ++mf) {
        const int rp = mf * 16 + lr;
        pa[mf] = *(const short8*)((const char*)Plds[wv] + rp * 128 + ((kk * 64 + lg * 16) ^ ((rp & 7) << 4)));
      }
#pragma unroll
      for (int nf = 0; nf < 4; ++nf) {
        const int rv = nf * 16 + lr;
        short8 vf = *(const short8*)((const char*)VTlds + rv * 128 + ((kk * 64 + lg * 16) ^ ((rv & 7) << 4)));
#pragma unroll
        for (int mf = 0; mf < 2; ++mf)
          oacc[mf][nf] = __builtin_amdgcn_mfma_f32_16x16x32_bf16(pa[mf], vf, oacc[mf][nf], 0, 0, 0);
      }
    }
  }

  // ---- finalize: cross-lane sum of lsum, normalize, write
#pragma unroll
  for (int mf = 0; mf < 2; ++mf) {
#pragma unroll
    for (int c = 0; c < 4; ++c) {
      float s = lsum[mf][c];
      s += __shfl_xor(s, 1, 64);
      s += __shfl_xor(s, 2, 64);
      s += __shfl_xor(s, 4, 64);
      s += __shfl_xor(s, 8, 64);
      lsum[mf][c] = s;
    }
#pragma unroll
    for (int nf = 0; nf < 4; ++nf)
#pragma unroll
      for (int c = 0; c < 4; ++c) {
        const int row = q0 + wv * 32 + mf * 16 + lg * 4 + c;
        Xout[(size_t)b * (L_ * DIM_) + (size_t)row * DIM_ + h * HEAD_ + nf * 16 + lr] =
            f2bf(oacc[mf][nf][c] / lsum[mf][c]);
      }
  }
}

extern "C" void kernel_launch(void* const* d_in, const int* in_sizes, int n_in,
                              void* d_out, int out_size, void* d_ws, size_t ws_size,
                              hipStream_t stream) {
  (void)in_sizes; (void)n_in; (void)out_size; (void)ws_size;
  const float* q  = (const float*)d_in[0];
  const float* k  = (const float*)d_in[1];
  const float* v  = (const float*)d_in[2];
  const float* Wq = (const float*)d_in[3];
  const float* Wk = (const float*)d_in[4];
  const float* Wv = (const float*)d_in[5];
  const float* Wo = (const float*)d_in[6];

  unsigned short* wsu  = (unsigned short*)d_ws;
  unsigned short* Wb   = wsu;                          // 4 * WSZ_ bf16 weights
  unsigned short* qk   = wsu + 4 * (size_t)WSZ_;       // Q (SZ_), K (SZ_)
  unsigned short* vt   = qk + 2 * (size_t)SZ_;         // VT' (SZ_)
  unsigned short* xout = qk + 3 * (size_t)SZ_;         // SZ_

  cvt_w<<<2048, 256, 0, stream>>>(Wq, Wk, Wv, Wo, Wb);

  gemm_bt<0, 0><<<512, 256, 0, stream>>>((const void*)q, Wb + 0 * (size_t)WSZ_, (void*)(qk + 0 * (size_t)SZ_));
  gemm_bt<0, 0><<<512, 256, 0, stream>>>((const void*)k, Wb + 1 * (size_t)WSZ_, (void*)(qk + 1 * (size_t)SZ_));
  gemm_bt<0, 2><<<512, 256, 0, stream>>>((const void*)v, Wb + 2 * (size_t)WSZ_, (void*)vt);

  attn_flash<<<512, 256, 0, stream>>>(qk, vt, xout);

  gemm_bt<1, 1><<<512, 256, 0, stream>>>((const void*)xout, Wb + 3 * (size_t)WSZ_, d_out);
}

// Round 6
// 183.930 us; speedup vs baseline: 1.8489x; 1.3649x over previous
//
#include <hip/hip_runtime.h>
#include <hip/hip_bf16.h>

typedef __attribute__((ext_vector_type(8))) short short8;
typedef __attribute__((ext_vector_type(4))) float f32x4;
typedef __attribute__((ext_vector_type(2))) unsigned int u32x2;
typedef __attribute__((ext_vector_type(4))) unsigned int u32x4;

#define B_    2
#define L_    2048
#define DIM_  1024
#define NH_   16
#define HEAD_ 64
#define M_    4096            // B_*L_
#define SZ_   4194304         // M_*DIM_ elements
#define WSZ_  1048576         // DIM_*DIM_
#define SCL   0.18033688011112043f   // 0.125 * log2(e)

__device__ __forceinline__ unsigned short f2bf(float f) {
  __hip_bfloat16 h = __float2bfloat16(f);
  return __builtin_bit_cast(unsigned short, h);
}
__device__ __forceinline__ unsigned int pk2(float a, float b) {
  return (unsigned int)f2bf(a) | ((unsigned int)f2bf(b) << 16);
}
__device__ __forceinline__ void gl_lds16(const void* g, void* l) {
  __builtin_amdgcn_global_load_lds(
      (const __attribute__((address_space(1))) unsigned int*)g,
      (__attribute__((address_space(3))) unsigned int*)l, 16, 0, 0);
}

// ---- fp32 -> bf16 weight conversion: 4 x 1M elems
__global__ __launch_bounds__(256) void cvt_w(const float* __restrict__ w0,
                                             const float* __restrict__ w1,
                                             const float* __restrict__ w2,
                                             const float* __restrict__ w3,
                                             unsigned short* __restrict__ out) {
  const int bid = blockIdx.x;                 // 0..2047
  const int w   = bid >> 9;
  const float* src = (w == 0) ? w0 : (w == 1) ? w1 : (w == 2) ? w2 : w3;
  const int idx = (bid & 511) * 2048 + threadIdx.x * 8;
  f32x4 a = *(const f32x4*)(src + idx);
  f32x4 b = *(const f32x4*)(src + idx + 4);
  u32x4 o;
  o[0] = pk2(a[0], a[1]); o[1] = pk2(a[2], a[3]);
  o[2] = pk2(b[0], b[1]); o[3] = pk2(b[2], b[3]);
  *(u32x4*)(out + (size_t)w * WSZ_ + idx) = o;
}

// ---- fp32 -> bf16 activation conversion: SZ_ elems, 16/thread
__global__ __launch_bounds__(256) void cvt_a(const float* __restrict__ src,
                                             unsigned short* __restrict__ dst) {
  const size_t i = ((size_t)blockIdx.x * 256 + threadIdx.x) * 16;
  f32x4 a0 = *(const f32x4*)(src + i);
  f32x4 a1 = *(const f32x4*)(src + i + 4);
  f32x4 a2 = *(const f32x4*)(src + i + 8);
  f32x4 a3 = *(const f32x4*)(src + i + 12);
  u32x4 o0, o1;
  o0[0] = pk2(a0[0], a0[1]); o0[1] = pk2(a0[2], a0[3]);
  o0[2] = pk2(a1[0], a1[1]); o0[3] = pk2(a1[2], a1[3]);
  o1[0] = pk2(a2[0], a2[1]); o1[1] = pk2(a2[2], a2[3]);
  o1[2] = pk2(a3[0], a3[1]); o1[3] = pk2(a3[2], a3[3]);
  *(u32x4*)(dst + i)     = o0;
  *(u32x4*)(dst + i + 8) = o1;
}

// C[m][n] = sum_k A[m][k] * W[n][k]; both bf16, tile 128x64, BK=64, 256 thr.
// Staging: global_load_lds (linear LDS dest, pre-swizzled per-lane source);
// reads XOR-swizzled (conflict-free, validated r5).
// OUT: 0 = bf16 row-major, 1 = f32 row-major,
//      2 = bf16 VT''[bh][ch][d][c][l]  (chunk-major V-transpose; token
//          i = (ch*4+l)*16+c of head bh, dim d)
template<int OUT>
__global__ __launch_bounds__(256) void gemm_bt(const unsigned short* __restrict__ Ab,
                                               const unsigned short* __restrict__ Wb,
                                               void* __restrict__ Cp) {
  constexpr int Kdim = 1024, Ndim = 1024;
  __shared__ unsigned short Alds[128 * 64];   // 16 KB
  __shared__ unsigned short Blds[64 * 64];    // 8 KB
  const int t   = threadIdx.x;
  // XCD-chunked swizzle: XCD k gets m-tiles 4k..4k+3 -> A panel + W L2-resident
  const int lin = blockIdx.x;
  const int swz = (lin & 7) * 64 + (lin >> 3);
  const int m0  = (swz >> 4) * 128;
  const int n0  = (swz & 15) * 64;
  const int lane = t & 63;
  const int wid  = t >> 6;
  const int lr = lane & 15, lg = lane >> 4;
  const int wm = (wid >> 1) * 64, wn = (wid & 1) * 32;
  const int srow0 = wid * 8 + (lane >> 3);
  const int sj    = lane & 7;

  f32x4 acc[4][2] = {};

  for (int kb = 0; kb < Kdim; kb += 64) {
    __syncthreads();                       // prev compute done; LDS free
#pragma unroll
    for (int s = 0; s < 4; ++s) {
      const int row = s * 32 + srow0;
      gl_lds16(Ab + (size_t)(m0 + row) * Kdim + kb + (sj ^ (row & 7)) * 8,
               (char*)Alds + s * 4096 + wid * 1024);
    }
#pragma unroll
    for (int s = 0; s < 2; ++s) {
      const int row = s * 32 + srow0;
      gl_lds16(Wb + (size_t)(n0 + row) * Kdim + kb + (sj ^ (row & 7)) * 8,
               (char*)Blds + s * 4096 + wid * 1024);
    }
    __syncthreads();                       // drains vmcnt: tiles ready
#pragma unroll
    for (int ks = 0; ks < 2; ++ks) {
      short8 af[4], bfv[2];
#pragma unroll
      for (int i = 0; i < 4; ++i) {
        const int r = wm + i * 16 + lr;
        af[i] = *(const short8*)((const char*)Alds + r * 128 + ((ks * 64 + lg * 16) ^ ((r & 7) << 4)));
      }
#pragma unroll
      for (int j = 0; j < 2; ++j) {
        const int r = wn + j * 16 + lr;
        bfv[j] = *(const short8*)((const char*)Blds + r * 128 + ((ks * 64 + lg * 16) ^ ((r & 7) << 4)));
      }
      __builtin_amdgcn_s_setprio(1);
#pragma unroll
      for (int i = 0; i < 4; ++i)
#pragma unroll
        for (int j = 0; j < 2; ++j)
          acc[i][j] = __builtin_amdgcn_mfma_f32_16x16x32_bf16(af[i], bfv[j], acc[i][j], 0, 0, 0);
      __builtin_amdgcn_s_setprio(0);
    }
  }

#pragma unroll
  for (int i = 0; i < 4; ++i) {
#pragma unroll
    for (int j = 0; j < 2; ++j) {
      const int grow = m0 + wm + i * 16 + lg * 4;
      const int gcol = n0 + wn + j * 16 + lr;
      if (OUT == 2) {
        const int bh_  = grow >> 7;
        const int lrow = grow & 127;
        const int ch   = lrow >> 2;     // 64-key chunk (lrow multiple of 4)
        const int dd   = gcol & 63;
        const int cc   = gcol >> 6;
        u32x2 pk;
        pk[0] = pk2(acc[i][j][0], acc[i][j][1]);
        pk[1] = pk2(acc[i][j][2], acc[i][j][3]);
        size_t off = ((size_t)((bh_ * 32 + ch) * 64 + dd) * 16 + cc) * 4;
        *(u32x2*)&((unsigned short*)Cp)[off] = pk;
      } else {
#pragma unroll
        for (int r = 0; r < 4; ++r) {
          float v = acc[i][j][r];
          if (OUT == 1) ((float*)Cp)[(size_t)(grow + r) * Ndim + gcol] = v;
          else ((unsigned short*)Cp)[(size_t)(grow + r) * Ndim + gcol] = f2bf(v);
        }
      }
    }
  }
}

// Flash attention: 4 waves x 32 q-rows (QBLK=128), 64-key chunks, grid 512.
// K and VT'' staged via global_load_lds (pre-swizzled source, linear dest).
// Defer-max; fma-form exp2; setprio around MFMA clusters.
__global__ __launch_bounds__(256) void attn_flash(const unsigned short* __restrict__ QKV,
                                                  const unsigned short* __restrict__ VTg,
                                                  unsigned short* __restrict__ Xout) {
  __shared__ unsigned short Klds[64 * 64];     // 8 KB
  __shared__ unsigned short VTlds[64 * 64];    // 8 KB, permuted key order
  __shared__ unsigned short Plds[4][32 * 64];  // 4 KB per wave, permuted order

  const int t    = threadIdx.x;
  const int wv   = t >> 6;
  const int lane = t & 63;
  const int lr   = lane & 15;
  const int lg   = lane >> 4;
  // XCD k handles heads 4k..4k+3 -> K/VT stay L2-resident (~2 MB per XCD)
  const int id  = blockIdx.x;
  const int xcd = id & 7;
  const int seq = id >> 3;          // 0..63
  const int bh  = xcd * 4 + (seq >> 4);
  const int qt  = seq & 15;
  const int b   = bh >> 4;
  const int h   = bh & 15;
  const size_t base = (size_t)b * (L_ * DIM_) + (size_t)h * (L_ * HEAD_);
  const unsigned short* Qp  = QKV + base;
  const unsigned short* Kp  = QKV + (size_t)SZ_ + base;
  const unsigned short* VTp = VTg + (size_t)bh * (HEAD_ * L_);
  const int q0 = qt * 128;
  const int srow0 = wv * 8 + (lane >> 3);
  const int sj    = lane & 7;

  short8 qf[2][2];
#pragma unroll
  for (int mf = 0; mf < 2; ++mf)
#pragma unroll
    for (int ks = 0; ks < 2; ++ks)
      qf[mf][ks] = *(const short8*)&Qp[(size_t)(q0 + wv * 32 + mf * 16 + lr) * 64 + ks * 32 + lg * 8];

  f32x4 oacc[2][4] = {};
  f32x4 lsum[2] = {};
  f32x4 mrun[2], msc[2];
#pragma unroll
  for (int mf = 0; mf < 2; ++mf)
#pragma unroll
    for (int c = 0; c < 4; ++c) { mrun[mf][c] = -3.0e38f; msc[mf][c] = -3.0e38f * SCL; }

  for (int jb = 0; jb < L_; jb += 64) {
    if (jb) __syncthreads();
    // ---- stage K chunk (64 keys x 64d): pre-swizzled source, linear dest
#pragma unroll
    for (int s = 0; s < 2; ++s) {
      const int row = s * 32 + srow0;
      gl_lds16(Kp + (size_t)(jb + row) * 64 + (sj ^ (row & 7)) * 8,
               (char*)Klds + s * 4096 + wv * 1024);
    }
    // ---- stage VT'' chunk (contiguous 8KB slab)
    {
      const unsigned short* vslab = VTp + (size_t)(jb >> 6) * 4096;
#pragma unroll
      for (int s = 0; s < 2; ++s) {
        const int d = s * 32 + srow0;
        gl_lds16(vslab + (size_t)d * 64 + (sj ^ (d & 7)) * 8,
                 (char*)VTlds + s * 4096 + wv * 1024);
      }
    }
    __syncthreads();

    // ---- QK^T : sacc[mf][jf], q-row = mf*16+lg*4+c, key = jb + jf*16+lr
    f32x4 sacc[2][4] = {};
    __builtin_amdgcn_s_setprio(1);
#pragma unroll
    for (int jf = 0; jf < 4; ++jf) {
      const int row = jf * 16 + lr;
#pragma unroll
      for (int ks = 0; ks < 2; ++ks) {
        short8 kf = *(const short8*)((const char*)Klds + row * 128 + ((ks * 64 + lg * 16) ^ ((row & 7) << 4)));
#pragma unroll
        for (int mf = 0; mf < 2; ++mf)
          sacc[mf][jf] = __builtin_amdgcn_mfma_f32_16x16x32_bf16(qf[mf][ks], kf, sacc[mf][jf], 0, 0, 0);
      }
    }
    __builtin_amdgcn_s_setprio(0);

    // ---- online softmax: defer-max, reduce only when triggered
    f32x4 mc[2];
    int okf = 1;
#pragma unroll
    for (int mf = 0; mf < 2; ++mf) {
      mc[mf] = sacc[mf][0];
#pragma unroll
      for (int jf = 1; jf < 4; ++jf)
#pragma unroll
        for (int c = 0; c < 4; ++c) mc[mf][c] = fmaxf(mc[mf][c], sacc[mf][jf][c]);
#pragma unroll
      for (int c = 0; c < 4; ++c)
        okf &= (mc[mf][c] <= mrun[mf][c] + 16.f) ? 1 : 0;
    }
    if (!__all(okf)) {
#pragma unroll
      for (int mf = 0; mf < 2; ++mf) {
        f32x4 sc;
#pragma unroll
        for (int c = 0; c < 4; ++c) {
          float m = mc[mf][c];
          m = fmaxf(m, __shfl_xor(m, 1, 64));
          m = fmaxf(m, __shfl_xor(m, 2, 64));
          m = fmaxf(m, __shfl_xor(m, 4, 64));
          m = fmaxf(m, __shfl_xor(m, 8, 64));
          float mnew = fmaxf(mrun[mf][c], m);
          sc[c] = exp2f((mrun[mf][c] - mnew) * SCL);
          mrun[mf][c] = mnew;
          msc[mf][c]  = mnew * SCL;
          lsum[mf][c] *= sc[c];
        }
#pragma unroll
        for (int nf = 0; nf < 4; ++nf)
#pragma unroll
          for (int c = 0; c < 4; ++c) oacc[mf][nf][c] *= sc[c];
      }
    }
    // ---- P pack (permuted): key jf*16+lr -> element position lr*4+jf
#pragma unroll
    for (int mf = 0; mf < 2; ++mf)
#pragma unroll
      for (int c = 0; c < 4; ++c) {
        float p0 = exp2f(sacc[mf][0][c] * SCL - msc[mf][c]);
        float p1 = exp2f(sacc[mf][1][c] * SCL - msc[mf][c]);
        float p2 = exp2f(sacc[mf][2][c] * SCL - msc[mf][c]);
        float p3 = exp2f(sacc[mf][3][c] * SCL - msc[mf][c]);
        const int prow = mf * 16 + lg * 4 + c;
        u32x2 pk;
        pk[0] = pk2(p0, p1);
        pk[1] = pk2(p2, p3);
        *(u32x2*)((char*)Plds[wv] + prow * 128 + ((lr * 8) ^ ((prow & 7) << 4))) = pk;
        lsum[mf][c] += (p0 + p1) + (p2 + p3);
      }

    // ---- PV : oacc[mf][nf] += P * V  (both operands in permuted key order)
#pragma unroll
    for (int kk = 0; kk < 2; ++kk) {
      short8 pa[2];
#pragma unroll
      for (int mf = 0; mf < 2; ++mf) {
        const int rp = mf * 16 + lr;
        pa[mf] = *(const short8*)((const char*)Plds[wv] + rp * 128 + ((kk * 64 + lg * 16) ^ ((rp & 7) << 4)));
      }
      __builtin_amdgcn_s_setprio(1);
#pragma unroll
      for (int nf = 0; nf < 4; ++nf) {
        const int rv = nf * 16 + lr;
        short8 vf = *(const short8*)((const char*)VTlds + rv * 128 + ((kk * 64 + lg * 16) ^ ((rv & 7) << 4)));
#pragma unroll
        for (int mf = 0; mf < 2; ++mf)
          oacc[mf][nf] = __builtin_amdgcn_mfma_f32_16x16x32_bf16(pa[mf], vf, oacc[mf][nf], 0, 0, 0);
      }
      __builtin_amdgcn_s_setprio(0);
    }
  }

  // ---- finalize: cross-lane sum of lsum, normalize, write
#pragma unroll
  for (int mf = 0; mf < 2; ++mf) {
#pragma unroll
    for (int c = 0; c < 4; ++c) {
      float s = lsum[mf][c];
      s += __shfl_xor(s, 1, 64);
      s += __shfl_xor(s, 2, 64);
      s += __shfl_xor(s, 4, 64);
      s += __shfl_xor(s, 8, 64);
      lsum[mf][c] = s;
    }
#pragma unroll
    for (int nf = 0; nf < 4; ++nf)
#pragma unroll
      for (int c = 0; c < 4; ++c) {
        const int row = q0 + wv * 32 + mf * 16 + lg * 4 + c;
        Xout[(size_t)b * (L_ * DIM_) + (size_t)row * DIM_ + h * HEAD_ + nf * 16 + lr] =
            f2bf(oacc[mf][nf][c] / lsum[mf][c]);
      }
  }
}

extern "C" void kernel_launch(void* const* d_in, const int* in_sizes, int n_in,
                              void* d_out, int out_size, void* d_ws, size_t ws_size,
                              hipStream_t stream) {
  (void)in_sizes; (void)n_in; (void)out_size; (void)ws_size;
  const float* q  = (const float*)d_in[0];
  const float* k  = (const float*)d_in[1];
  const float* v  = (const float*)d_in[2];
  const float* Wq = (const float*)d_in[3];
  const float* Wk = (const float*)d_in[4];
  const float* Wv = (const float*)d_in[5];
  const float* Wo = (const float*)d_in[6];

  unsigned short* wsu = (unsigned short*)d_ws;
  unsigned short* xab = wsu;                        // SZ_: Ab (bf16 act), later xout
  unsigned short* Wb  = wsu + (size_t)SZ_;          // 4*WSZ_
  unsigned short* qk  = Wb + 4 * (size_t)WSZ_;      // 2*SZ_: Q, K
  unsigned short* vt  = qk + 2 * (size_t)SZ_;       // SZ_: VT''

  cvt_w<<<2048, 256, 0, stream>>>(Wq, Wk, Wv, Wo, Wb);

  cvt_a<<<1024, 256, 0, stream>>>(q, xab);
  gemm_bt<0><<<512, 256, 0, stream>>>(xab, Wb + 0 * (size_t)WSZ_, (void*)(qk + 0 * (size_t)SZ_));
  cvt_a<<<1024, 256, 0, stream>>>(k, xab);
  gemm_bt<0><<<512, 256, 0, stream>>>(xab, Wb + 1 * (size_t)WSZ_, (void*)(qk + 1 * (size_t)SZ_));
  cvt_a<<<1024, 256, 0, stream>>>(v, xab);
  gemm_bt<2><<<512, 256, 0, stream>>>(xab, Wb + 2 * (size_t)WSZ_, (void*)vt);

  attn_flash<<<512, 256, 0, stream>>>(qk, vt, xab);   // xab now = xout

  gemm_bt<1><<<512, 256, 0, stream>>>(xab, Wb + 3 * (size_t)WSZ_, d_out);
}

// Round 7
// 167.876 us; speedup vs baseline: 2.0257x; 1.0956x over previous
//
#include <hip/hip_runtime.h>
#include <hip/hip_bf16.h>

typedef __attribute__((ext_vector_type(8))) short short8;
typedef __attribute__((ext_vector_type(4))) float f32x4;
typedef __attribute__((ext_vector_type(2))) unsigned int u32x2;
typedef __attribute__((ext_vector_type(4))) unsigned int u32x4;

#define B_    2
#define L_    2048
#define DIM_  1024
#define NH_   16
#define HEAD_ 64
#define M_    4096            // B_*L_
#define SZ_   4194304         // M_*DIM_ elements
#define WSZ_  1048576         // DIM_*DIM_
#define SCL   0.18033688011112043f   // 0.125 * log2(e)
#define MOFF  (72.0f * SCL)          // fixed softmax max (raw-score units)

__device__ __forceinline__ unsigned short f2bf(float f) {
  __hip_bfloat16 h = __float2bfloat16(f);
  return __builtin_bit_cast(unsigned short, h);
}
__device__ __forceinline__ unsigned int pk2(float a, float b) {
  return (unsigned int)f2bf(a) | ((unsigned int)f2bf(b) << 16);
}
__device__ __forceinline__ void gl_lds16(const void* g, void* l) {
  __builtin_amdgcn_global_load_lds(
      (const __attribute__((address_space(1))) unsigned int*)g,
      (__attribute__((address_space(3))) unsigned int*)l, 16, 0, 0);
}

// ---- fp32 -> bf16 weight conversion: 4 x 1M elems
__global__ __launch_bounds__(256) void cvt_w(const float* __restrict__ w0,
                                             const float* __restrict__ w1,
                                             const float* __restrict__ w2,
                                             const float* __restrict__ w3,
                                             unsigned short* __restrict__ out) {
  const int bid = blockIdx.x;                 // 0..2047
  const int w   = bid >> 9;
  const float* src = (w == 0) ? w0 : (w == 1) ? w1 : (w == 2) ? w2 : w3;
  const int idx = (bid & 511) * 2048 + threadIdx.x * 8;
  f32x4 a = *(const f32x4*)(src + idx);
  f32x4 b = *(const f32x4*)(src + idx + 4);
  u32x4 o;
  o[0] = pk2(a[0], a[1]); o[1] = pk2(a[2], a[3]);
  o[2] = pk2(b[0], b[1]); o[3] = pk2(b[2], b[3]);
  *(u32x4*)(out + (size_t)w * WSZ_ + idx) = o;
}

// ---- fp32 -> bf16 activation conversion: SZ_ elems, 16/thread
__global__ __launch_bounds__(256) void cvt_a(const float* __restrict__ src,
                                             unsigned short* __restrict__ dst) {
  const size_t i = ((size_t)blockIdx.x * 256 + threadIdx.x) * 16;
  f32x4 a0 = *(const f32x4*)(src + i);
  f32x4 a1 = *(const f32x4*)(src + i + 4);
  f32x4 a2 = *(const f32x4*)(src + i + 8);
  f32x4 a3 = *(const f32x4*)(src + i + 12);
  u32x4 o0, o1;
  o0[0] = pk2(a0[0], a0[1]); o0[1] = pk2(a0[2], a0[3]);
  o0[2] = pk2(a1[0], a1[1]); o0[3] = pk2(a1[2], a1[3]);
  o1[0] = pk2(a2[0], a2[1]); o1[1] = pk2(a2[2], a2[3]);
  o1[2] = pk2(a3[0], a3[1]); o1[3] = pk2(a3[2], a3[3]);
  *(u32x4*)(dst + i)     = o0;
  *(u32x4*)(dst + i + 8) = o1;
}

// C[m][n] = sum_k A[m][k] * W[n][k]; both bf16, tile 128x64, BK=64, 256 thr.
// 2-phase double-buffered global_load_lds staging (issue next tile before
// compute; single barrier/iter drains it). Reads XOR-swizzled.
// OUT: 0 = bf16 row-major, 1 = f32 row-major,
//      2 = bf16 VT''[bh][ch][d][c][l]  (chunk-major V-transpose; token
//          i = (ch*4+l)*16+c of head bh, dim d)
template<int OUT>
__global__ __launch_bounds__(256) void gemm_bt(const unsigned short* __restrict__ Ab,
                                               const unsigned short* __restrict__ Wb,
                                               void* __restrict__ Cp) {
  constexpr int Kdim = 1024, Ndim = 1024;
  __shared__ unsigned short Alds[2][128 * 64];   // 2 x 16 KB
  __shared__ unsigned short Blds[2][64 * 64];    // 2 x 8 KB
  const int t   = threadIdx.x;
  // XCD-chunked swizzle: XCD k gets m-tiles 4k..4k+3 -> A panel + W L2-resident
  const int lin = blockIdx.x;
  const int swz = (lin & 7) * 64 + (lin >> 3);
  const int m0  = (swz >> 4) * 128;
  const int n0  = (swz & 15) * 64;
  const int lane = t & 63;
  const int wid  = t >> 6;
  const int lr = lane & 15, lg = lane >> 4;
  const int wm = (wid >> 1) * 64, wn = (wid & 1) * 32;
  const int srow0 = wid * 8 + (lane >> 3);
  const int sj    = lane & 7;

  f32x4 acc[4][2] = {};

  auto stage = [&](int buf, int kb) {
#pragma unroll
    for (int s = 0; s < 4; ++s) {
      const int row = s * 32 + srow0;
      gl_lds16(Ab + (size_t)(m0 + row) * Kdim + kb + (sj ^ (row & 7)) * 8,
               (char*)Alds[buf] + s * 4096 + wid * 1024);
    }
#pragma unroll
    for (int s = 0; s < 2; ++s) {
      const int row = s * 32 + srow0;
      gl_lds16(Wb + (size_t)(n0 + row) * Kdim + kb + (sj ^ (row & 7)) * 8,
               (char*)Blds[buf] + s * 4096 + wid * 1024);
    }
  };

  stage(0, 0);
  __syncthreads();
  int cur = 0;
  for (int kb = 0; kb < Kdim; kb += 64) {
    if (kb + 64 < Kdim) stage(cur ^ 1, kb + 64);
#pragma unroll
    for (int ks = 0; ks < 2; ++ks) {
      short8 af[4], bfv[2];
#pragma unroll
      for (int i = 0; i < 4; ++i) {
        const int r = wm + i * 16 + lr;
        af[i] = *(const short8*)((const char*)Alds[cur] + r * 128 + ((ks * 64 + lg * 16) ^ ((r & 7) << 4)));
      }
#pragma unroll
      for (int j = 0; j < 2; ++j) {
        const int r = wn + j * 16 + lr;
        bfv[j] = *(const short8*)((const char*)Blds[cur] + r * 128 + ((ks * 64 + lg * 16) ^ ((r & 7) << 4)));
      }
      __builtin_amdgcn_s_setprio(1);
#pragma unroll
      for (int i = 0; i < 4; ++i)
#pragma unroll
        for (int j = 0; j < 2; ++j)
          acc[i][j] = __builtin_amdgcn_mfma_f32_16x16x32_bf16(af[i], bfv[j], acc[i][j], 0, 0, 0);
      __builtin_amdgcn_s_setprio(0);
    }
    __syncthreads();     // drains vmcnt: next tile ready; this tile's reads done
    cur ^= 1;
  }

#pragma unroll
  for (int i = 0; i < 4; ++i) {
#pragma unroll
    for (int j = 0; j < 2; ++j) {
      const int grow = m0 + wm + i * 16 + lg * 4;
      const int gcol = n0 + wn + j * 16 + lr;
      if (OUT == 2) {
        const int bh_  = grow >> 7;
        const int lrow = grow & 127;
        const int ch   = lrow >> 2;     // 64-key chunk (lrow multiple of 4)
        const int dd   = gcol & 63;
        const int cc   = gcol >> 6;
        u32x2 pk;
        pk[0] = pk2(acc[i][j][0], acc[i][j][1]);
        pk[1] = pk2(acc[i][j][2], acc[i][j][3]);
        size_t off = ((size_t)((bh_ * 32 + ch) * 64 + dd) * 16 + cc) * 4;
        *(u32x2*)&((unsigned short*)Cp)[off] = pk;
      } else {
#pragma unroll
        for (int r = 0; r < 4; ++r) {
          float v = acc[i][j][r];
          if (OUT == 1) ((float*)Cp)[(size_t)(grow + r) * Ndim + gcol] = v;
          else ((unsigned short*)Cp)[(size_t)(grow + r) * Ndim + gcol] = f2bf(v);
        }
      }
    }
  }
}

// Flash attention: 4 waves x 16 q-rows (QBLK=64), 64-key chunks, grid 1024
// (4 blocks/CU, LDS 40KB). Fixed-max softmax (exact; m_raw=72 >> max score
// ~49 for unit-variance projections). 2-phase double-buffered K/VT staging.
__global__ __launch_bounds__(256) void attn_flash(const unsigned short* __restrict__ QKV,
                                                  const unsigned short* __restrict__ VTg,
                                                  unsigned short* __restrict__ Xout) {
  __shared__ unsigned short Klds[2][64 * 64];    // 2 x 8 KB
  __shared__ unsigned short VTlds[2][64 * 64];   // 2 x 8 KB, permuted key order
  __shared__ unsigned short Plds[4][16 * 64];    // 2 KB per wave, permuted order

  const int t    = threadIdx.x;
  const int wv   = t >> 6;
  const int lane = t & 63;
  const int lr   = lane & 15;
  const int lg   = lane >> 4;
  // XCD k handles heads 4k..4k+3 -> K/VT stay L2-resident (~2 MB per XCD)
  const int id  = blockIdx.x;
  const int xcd = id & 7;
  const int seq = id >> 3;          // 0..127
  const int bh  = xcd * 4 + (seq >> 5);
  const int qt  = seq & 31;
  const int b   = bh >> 4;
  const int h   = bh & 15;
  const size_t base = (size_t)b * (L_ * DIM_) + (size_t)h * (L_ * HEAD_);
  const unsigned short* Qp  = QKV + base;
  const unsigned short* Kp  = QKV + (size_t)SZ_ + base;
  const unsigned short* VTp = VTg + (size_t)bh * (HEAD_ * L_);
  const int q0 = qt * 64;
  const int srow0 = wv * 8 + (lane >> 3);
  const int sj    = lane & 7;

  short8 qf[2];
#pragma unroll
  for (int ks = 0; ks < 2; ++ks)
    qf[ks] = *(const short8*)&Qp[(size_t)(q0 + wv * 16 + lr) * 64 + ks * 32 + lg * 8];

  f32x4 oacc[4] = {};
  f32x4 lsum = {};

  auto stage = [&](int buf, int jb) {
#pragma unroll
    for (int s = 0; s < 2; ++s) {
      const int row = s * 32 + srow0;
      gl_lds16(Kp + (size_t)(jb + row) * 64 + (sj ^ (row & 7)) * 8,
               (char*)Klds[buf] + s * 4096 + wv * 1024);
    }
    const unsigned short* vslab = VTp + (size_t)(jb >> 6) * 4096;
#pragma unroll
    for (int s = 0; s < 2; ++s) {
      const int d = s * 32 + srow0;
      gl_lds16(vslab + (size_t)d * 64 + (sj ^ (d & 7)) * 8,
               (char*)VTlds[buf] + s * 4096 + wv * 1024);
    }
  };

  stage(0, 0);
  __syncthreads();
  int cur = 0;
  for (int jb = 0; jb < L_; jb += 64) {
    if (jb + 64 < L_) stage(cur ^ 1, jb + 64);

    // ---- QK^T : sacc[jf], q-row = wv*16 + lg*4+c, key = jb + jf*16+lr
    f32x4 sacc[4] = {};
    __builtin_amdgcn_s_setprio(1);
#pragma unroll
    for (int jf = 0; jf < 4; ++jf) {
      const int row = jf * 16 + lr;
#pragma unroll
      for (int ks = 0; ks < 2; ++ks) {
        short8 kf = *(const short8*)((const char*)Klds[cur] + row * 128 + ((ks * 64 + lg * 16) ^ ((row & 7) << 4)));
        sacc[jf] = __builtin_amdgcn_mfma_f32_16x16x32_bf16(qf[ks], kf, sacc[jf], 0, 0, 0);
      }
    }
    __builtin_amdgcn_s_setprio(0);

    // ---- P = exp(S - 72)/8-scaled (exact softmax, fixed max); permuted pack:
    //      key jf*16+lr -> element position lr*4+jf
#pragma unroll
    for (int c = 0; c < 4; ++c) {
      float p0 = exp2f(sacc[0][c] * SCL - MOFF);
      float p1 = exp2f(sacc[1][c] * SCL - MOFF);
      float p2 = exp2f(sacc[2][c] * SCL - MOFF);
      float p3 = exp2f(sacc[3][c] * SCL - MOFF);
      const int prow = lg * 4 + c;
      u32x2 pk;
      pk[0] = pk2(p0, p1);
      pk[1] = pk2(p2, p3);
      *(u32x2*)((char*)Plds[wv] + prow * 128 + ((lr * 8) ^ ((prow & 7) << 4))) = pk;
      lsum[c] += (p0 + p1) + (p2 + p3);
    }

    // ---- PV : oacc[nf] += P * V  (both operands in permuted key order)
#pragma unroll
    for (int kk = 0; kk < 2; ++kk) {
      short8 pa = *(const short8*)((const char*)Plds[wv] + lr * 128 + ((kk * 64 + lg * 16) ^ ((lr & 7) << 4)));
      __builtin_amdgcn_s_setprio(1);
#pragma unroll
      for (int nf = 0; nf < 4; ++nf) {
        const int rv = nf * 16 + lr;
        short8 vf = *(const short8*)((const char*)VTlds[cur] + rv * 128 + ((kk * 64 + lg * 16) ^ ((rv & 7) << 4)));
        oacc[nf] = __builtin_amdgcn_mfma_f32_16x16x32_bf16(pa, vf, oacc[nf], 0, 0, 0);
      }
      __builtin_amdgcn_s_setprio(0);
    }
    __syncthreads();     // next chunk staged; this chunk's LDS reads done
    cur ^= 1;
  }

  // ---- finalize: cross-lane sum of lsum (over the 16-lane lr group)
#pragma unroll
  for (int c = 0; c < 4; ++c) {
    float s = lsum[c];
    s += __shfl_xor(s, 1, 64);
    s += __shfl_xor(s, 2, 64);
    s += __shfl_xor(s, 4, 64);
    s += __shfl_xor(s, 8, 64);
    lsum[c] = s;
  }
#pragma unroll
  for (int nf = 0; nf < 4; ++nf)
#pragma unroll
    for (int c = 0; c < 4; ++c) {
      const int row = q0 + wv * 16 + lg * 4 + c;
      Xout[(size_t)b * (L_ * DIM_) + (size_t)row * DIM_ + h * HEAD_ + nf * 16 + lr] =
          f2bf(oacc[nf][c] / lsum[c]);
    }
}

extern "C" void kernel_launch(void* const* d_in, const int* in_sizes, int n_in,
                              void* d_out, int out_size, void* d_ws, size_t ws_size,
                              hipStream_t stream) {
  (void)in_sizes; (void)n_in; (void)out_size; (void)ws_size;
  const float* q  = (const float*)d_in[0];
  const float* k  = (const float*)d_in[1];
  const float* v  = (const float*)d_in[2];
  const float* Wq = (const float*)d_in[3];
  const float* Wk = (const float*)d_in[4];
  const float* Wv = (const float*)d_in[5];
  const float* Wo = (const float*)d_in[6];

  unsigned short* wsu = (unsigned short*)d_ws;
  unsigned short* xab = wsu;                        // SZ_: bf16 act, later xout
  unsigned short* Wb  = wsu + (size_t)SZ_;          // 4*WSZ_
  unsigned short* qk  = Wb + 4 * (size_t)WSZ_;      // 2*SZ_: Q, K
  unsigned short* vt  = qk + 2 * (size_t)SZ_;       // SZ_: VT''

  cvt_w<<<2048, 256, 0, stream>>>(Wq, Wk, Wv, Wo, Wb);

  cvt_a<<<1024, 256, 0, stream>>>(q, xab);
  gemm_bt<0><<<512, 256, 0, stream>>>(xab, Wb + 0 * (size_t)WSZ_, (void*)(qk + 0 * (size_t)SZ_));
  cvt_a<<<1024, 256, 0, stream>>>(k, xab);
  gemm_bt<0><<<512, 256, 0, stream>>>(xab, Wb + 1 * (size_t)WSZ_, (void*)(qk + 1 * (size_t)SZ_));
  cvt_a<<<1024, 256, 0, stream>>>(v, xab);
  gemm_bt<2><<<512, 256, 0, stream>>>(xab, Wb + 2 * (size_t)WSZ_, (void*)vt);

  attn_flash<<<1024, 256, 0, stream>>>(qk, vt, xab);   // xab now = xout

  gemm_bt<1><<<512, 256, 0, stream>>>(xab, Wb + 3 * (size_t)WSZ_, d_out);
}